// Round 5
// baseline (429.575 us; speedup 1.0000x reference)
//
#include <hip/hip_runtime.h>
#include <cstdint>
#include <cstddef>

// SpectralConv2d: out = real(ifft2(concat[einsum(fft2(x)[:, :64], w1),
//                                         zeros, einsum(fft2(x)[:, -64:], w2)]))
// B=16, S1=512, S2=64, M2=64, in=out=m1=m2=64.
//
// ws layout (needs 134 MB):
//   XFT_re [128j][16b][64kx][64ky] fp32   (33.5 MB)   j<64 -> s1=j ; j>=64 -> s1=384+j
//   XFT_im                                 (33.5 MB)
//   OFT_re [2set][16b][64o][64kx][64ky]    (33.5 MB)
//   OFT_im                                 (33.5 MB)

#define TWO_PI 6.283185307179586f

__device__ __forceinline__ constexpr int bitrev6(int x) {
    return ((x & 1) << 5) | ((x & 2) << 3) | ((x & 4) << 1) |
           ((x & 8) >> 1) | ((x & 16) >> 3) | ((x & 32) >> 5);
}

// In-register 64-point FFT, input already bit-reversed, output natural order.
__device__ __forceinline__ void fft64_reg(float* re, float* im,
                                          const float* twc, const float* tws) {
#pragma unroll
    for (int s = 1; s <= 6; ++s) {
        const int m = 1 << s;
        const int h = m >> 1;
        const int step = 64 >> s;
#pragma unroll
        for (int k = 0; k < 64; k += m) {
#pragma unroll
            for (int j = 0; j < h; ++j) {
                const float wr = twc[j * step];
                const float wi = tws[j * step];
                const int p = k + j, q = p + h;
                const float tr = re[q] * wr - im[q] * wi;
                const float ti = re[q] * wi + im[q] * wr;
                re[q] = re[p] - tr; im[q] = im[p] - ti;
                re[p] = re[p] + tr; im[p] = im[p] + ti;
            }
        }
    }
}

// ---------------- forward: 2D FFT of 64x64 real tile ----------------
__global__ __launch_bounds__(64, 1) void fwd_fft_kernel(const float* __restrict__ x,
                                                        float* __restrict__ xre,
                                                        float* __restrict__ xim) {
    __shared__ float lre[64 * 65];
    __shared__ float lim[64 * 65];
    __shared__ float twc[64];
    __shared__ float tws[64];
    const int t = threadIdx.x;
    const int j = blockIdx.x & 127;
    const int b = blockIdx.x >> 7;
    const int s1 = (j < 64) ? j : (384 + j);

    const float ang = (TWO_PI / 64.0f) * (float)t;
    twc[t] = cosf(ang);
    tws[t] = -sinf(ang);   // forward

    const float* __restrict__ src = x + ((size_t)(b * 512 + s1)) * 4096;
#pragma unroll
    for (int k = 0; k < 64; ++k) lre[k * 65 + t] = src[k * 64 + t];  // coalesced
    __syncthreads();

    float are[64], aim[64];
#pragma unroll
    for (int q = 0; q < 64; ++q) { are[q] = lre[t * 65 + bitrev6(q)]; aim[q] = 0.0f; }
    fft64_reg(are, aim, twc, tws);
#pragma unroll
    for (int q = 0; q < 64; ++q) { lre[t * 65 + q] = are[q]; lim[t * 65 + q] = aim[q]; }
    __syncthreads();

#pragma unroll
    for (int q = 0; q < 64; ++q) {
        const int r = bitrev6(q);
        are[q] = lre[r * 65 + t];
        aim[q] = lim[r * 65 + t];
    }
    fft64_reg(are, aim, twc, tws);

    float* __restrict__ dre = xre + (size_t)(j * 16 + b) * 4096;
    float* __restrict__ dim_ = xim + (size_t)(j * 16 + b) * 4096;
#pragma unroll
    for (int kp = 0; kp < 64; ++kp) {
        dre[kp * 64 + t] = are[kp];
        dim_[kp * 64 + t] = aim[kp];
    }
}

// ---------------- channel mix: LDS-staged batched GEMM ----------------
// grid (kx*4+kyChunk = 256, o-half = 2, set = 2) = 1024 blocks, 256 thr.
// Block: all 16 b, 32 o, 16 ky, 64 i.  W read exactly once globally.
// Double-buffered LDS chunks of IC=4 i-steps staged via global_load_lds(16B).
// LDS unit layouts (float4 units): X: [kyq][bb][bq] -> reader's 32 distinct
// b128 addrs cover all 8 bank-groups 4-deep (minimum); W: [o][kyq] (<=2-way).
#define IC 4
#define NCH 16

__device__ __forceinline__ void fma4(float4& a, const float4& x, const float4& w) {
    a.x += x.x * w.x; a.y += x.y * w.y; a.z += x.z * w.z; a.w += x.w * w.w;
}

__device__ __forceinline__ void gl_lds16(const void* g, void* l) {
    __builtin_amdgcn_global_load_lds((const __attribute__((address_space(1))) void*)g,
                                     (__attribute__((address_space(3))) void*)l, 16, 0, 0);
}

__global__ __launch_bounds__(256, 4) void mix_kernel(const float* __restrict__ xre,
                                                     const float* __restrict__ xim,
                                                     const float* __restrict__ w1,
                                                     const float* __restrict__ w2,
                                                     float* __restrict__ ore,
                                                     float* __restrict__ oim) {
    __shared__ float4 sW[2][IC][128];   // [buf][ii][o*4 + kyq]            16 KB
    __shared__ float4 sXr[2][IC][64];   // [buf][ii][kyq*16 + bb*8 + bq]    8 KB
    __shared__ float4 sXi[2][IC][64];   //                                  8 KB

    const int t = threadIdx.x;
    const int kyq = t & 3;          // ky quad (float4)
    const int u = t >> 2;
    const int bq = u & 7;           // b = 2*bq + bb
    const int oq = u >> 3;          // o = o0 + oq*4 + oo
    const int wv = t >> 6;
    const int l = t & 63;

    const int kx = blockIdx.x >> 2;
    const int ky0 = (blockIdx.x & 3) * 16;
    const int o0 = blockIdx.y * 32;
    const int set = blockIdx.z;
    const float* __restrict__ w = set ? w2 : w1;
    const int fx = kx * 64 + ky0;

    // staging lane geometry
    const int sw_o = l >> 2;                            // W waves: o within half
    const int sw_k = l & 3;
    const int sx_b = 2 * (l & 7) + ((l >> 3) & 1);      // X waves: b for unit p=l
    const int sx_k = l >> 4;                            // ky quad for unit p=l

    const float* __restrict__ xrB = xre + (size_t)(set * 64) * 16 * 4096 + fx;
    const float* __restrict__ xiB = xim + (size_t)(set * 64) * 16 * 4096 + fx;
    const float* __restrict__ wB  = w + (size_t)o0 * 4096 + fx;

    auto stage = [&](int sbuf, int c) {
        const int i0 = c * IC;
        if (wv < 2) {                       // 8 W wave-loads: (ii,half)
#pragma unroll
            for (int jj = 0; jj < 4; ++jj) {
                const int flat = wv * 4 + jj;
                const int ii = flat >> 1;
                const int half = flat & 1;
                const float* g = wB + (size_t)((i0 + ii) * 64 + half * 16 + sw_o) * 4096 + sw_k * 4;
                gl_lds16(g, &sW[sbuf][ii][half * 64]);
            }
        } else if (wv == 2) {               // X real
#pragma unroll
            for (int ii = 0; ii < IC; ++ii) {
                const float* g = xrB + (size_t)((i0 + ii) * 16 + sx_b) * 4096 + sx_k * 4;
                gl_lds16(g, &sXr[sbuf][ii][0]);
            }
        } else {                            // X imag
#pragma unroll
            for (int ii = 0; ii < IC; ++ii) {
                const float* g = xiB + (size_t)((i0 + ii) * 16 + sx_b) * 4096 + sx_k * 4;
                gl_lds16(g, &sXi[sbuf][ii][0]);
            }
        }
    };

    float4 accRe[2][4] = {};
    float4 accIm[2][4] = {};

    const int xp0 = kyq * 16 + bq;      // bb=0 unit
    const int wp0 = oq * 16 + kyq;      // oo=0 unit

    stage(0, 0);
    __syncthreads();

    int buf = 0;
#pragma unroll 1
    for (int c = 0; c < NCH; ++c) {
        if (c + 1 < NCH) stage(buf ^ 1, c + 1);
        __builtin_amdgcn_sched_barrier(0);   // keep stage-issue above compute
#pragma unroll
        for (int ii = 0; ii < IC; ++ii) {
            const float4 xr0 = sXr[buf][ii][xp0];
            const float4 xr1 = sXr[buf][ii][xp0 + 8];
            const float4 xi0 = sXi[buf][ii][xp0];
            const float4 xi1 = sXi[buf][ii][xp0 + 8];
            float4 wq[4];
#pragma unroll
            for (int oo = 0; oo < 4; ++oo) wq[oo] = sW[buf][ii][wp0 + oo * 4];
#pragma unroll
            for (int oo = 0; oo < 4; ++oo) {
                fma4(accRe[0][oo], xr0, wq[oo]);
                fma4(accRe[1][oo], xr1, wq[oo]);
                fma4(accIm[0][oo], xi0, wq[oo]);
                fma4(accIm[1][oo], xi1, wq[oo]);
            }
        }
        __syncthreads();
        buf ^= 1;
    }

#pragma unroll
    for (int bb = 0; bb < 2; ++bb)
#pragma unroll
        for (int oo = 0; oo < 4; ++oo) {
            const size_t pl = (size_t)set * 1024 + (size_t)(bq * 2 + bb) * 64 + (o0 + oq * 4 + oo);
            const size_t q = (pl << 12) + fx + kyq * 4;
            *(float4*)(ore + q) = accRe[bb][oo];
            *(float4*)(oim + q) = accIm[bb][oo];
        }
}

// ---------------- inverse: 2D IFFT (complex->real) of 64x64 plane ----------------
__global__ __launch_bounds__(64, 1) void inv_fft_kernel(const float* __restrict__ ore,
                                                        const float* __restrict__ oim,
                                                        float* __restrict__ out) {
    __shared__ float lre[64 * 65];
    __shared__ float lim[64 * 65];
    __shared__ float twc[64];
    __shared__ float tws[64];
    const int t = threadIdx.x;
    const int pl = blockIdx.x;
    const int set = pl >> 10;
    const int b = (pl >> 6) & 15;
    const int o = pl & 63;

    const float ang = (TWO_PI / 64.0f) * (float)t;
    twc[t] = cosf(ang);
    tws[t] = sinf(ang);    // inverse

    const float* __restrict__ sre = ore + (size_t)pl * 4096;
    const float* __restrict__ sim = oim + (size_t)pl * 4096;
#pragma unroll
    for (int k = 0; k < 64; ++k) {
        lre[k * 65 + t] = sre[k * 64 + t];
        lim[k * 65 + t] = sim[k * 64 + t];
    }
    __syncthreads();

    float are[64], aim[64];
#pragma unroll
    for (int q = 0; q < 64; ++q) {
        const int r = bitrev6(q);
        are[q] = lre[t * 65 + r];
        aim[q] = lim[t * 65 + r];
    }
    fft64_reg(are, aim, twc, tws);
#pragma unroll
    for (int q = 0; q < 64; ++q) { lre[t * 65 + q] = are[q]; lim[t * 65 + q] = aim[q]; }
    __syncthreads();

#pragma unroll
    for (int q = 0; q < 64; ++q) {
        const int r = bitrev6(q);
        are[q] = lre[r * 65 + t];
        aim[q] = lim[r * 65 + t];
    }
    fft64_reg(are, aim, twc, tws);

    const int s1 = set ? (448 + o) : o;
    float* __restrict__ dst = out + ((size_t)(b * 512 + s1)) * 4096;
#pragma unroll
    for (int p = 0; p < 64; ++p)
        dst[p * 64 + t] = are[p] * (1.0f / 4096.0f);
}

// ---------------- zero-fill out[:, 64:448, :, :] ----------------
__global__ void zero_mid_kernel(float4* __restrict__ out) {
    const size_t per_b = (size_t)384 * 1024;  // float4 per batch mid-region
    const size_t i = (size_t)blockIdx.x * blockDim.x + threadIdx.x;
    if (i >= 16 * per_b) return;
    const size_t b = i / per_b;
    const size_t r = i - b * per_b;
    out[b * (512 * 1024) + 64 * 1024 + r] = make_float4(0.f, 0.f, 0.f, 0.f);
}

extern "C" void kernel_launch(void* const* d_in, const int* in_sizes, int n_in,
                              void* d_out, int out_size, void* d_ws, size_t ws_size,
                              hipStream_t stream) {
    const float* x  = (const float*)d_in[0];
    const float* w1 = (const float*)d_in[1];
    const float* w2 = (const float*)d_in[2];
    float* out = (float*)d_out;

    const size_t PLANE_FLOATS = (size_t)2048 * 4096;  // 33.5 MB each
    float* xre = (float*)d_ws;
    float* xim = xre + PLANE_FLOATS;
    float* ore = xim + PLANE_FLOATS;
    float* oim = ore + PLANE_FLOATS;
    // requires ws_size >= 134 MB

    fwd_fft_kernel<<<2048, 64, 0, stream>>>(x, xre, xim);
    mix_kernel<<<dim3(256, 2, 2), 256, 0, stream>>>(xre, xim, w1, w2, ore, oim);
    inv_fft_kernel<<<2048, 64, 0, stream>>>(ore, oim, out);

    const int zthreads = 256;
    const int zblocks = (int)(((size_t)16 * 384 * 1024 + zthreads - 1) / zthreads);
    zero_mid_kernel<<<zblocks, zthreads, 0, stream>>>((float4*)out);
}

// Round 6
// 214.064 us; speedup vs baseline: 2.0068x; 2.0068x over previous
//
#include <hip/hip_runtime.h>
#include <cstdint>
#include <cstddef>

// SpectralConv2d: out = real(ifft2(concat[einsum(fft2(x)[:, :64], w1),
//                                         zeros, einsum(fft2(x)[:, -64:], w2)]))
// B=16, S1=512, S2=64, M2=64, in=out=m1=m2=64.
//
// ws layout (needs 134 MB):
//   XFT_re [128j][16b][64kx][64ky] fp32   (33.5 MB)   j<64 -> s1=j ; j>=64 -> s1=384+j
//   XFT_im                                 (33.5 MB)
//   OFT_re [2set][16b][64o][64kx][64ky]    (33.5 MB)
//   OFT_im                                 (33.5 MB)

#define TWO_PI 6.283185307179586f

__device__ __forceinline__ constexpr int bitrev6(int x) {
    return ((x & 1) << 5) | ((x & 2) << 3) | ((x & 4) << 1) |
           ((x & 8) >> 1) | ((x & 16) >> 3) | ((x & 32) >> 5);
}

// In-register 64-point FFT, input already bit-reversed, output natural order.
__device__ __forceinline__ void fft64_reg(float* re, float* im,
                                          const float* twc, const float* tws) {
#pragma unroll
    for (int s = 1; s <= 6; ++s) {
        const int m = 1 << s;
        const int h = m >> 1;
        const int step = 64 >> s;
#pragma unroll
        for (int k = 0; k < 64; k += m) {
#pragma unroll
            for (int j = 0; j < h; ++j) {
                const float wr = twc[j * step];
                const float wi = tws[j * step];
                const int p = k + j, q = p + h;
                const float tr = re[q] * wr - im[q] * wi;
                const float ti = re[q] * wi + im[q] * wr;
                re[q] = re[p] - tr; im[q] = im[p] - ti;
                re[p] = re[p] + tr; im[p] = im[p] + ti;
            }
        }
    }
}

// ---------------- forward: 2D FFT of 64x64 real tile ----------------
__global__ __launch_bounds__(64, 1) void fwd_fft_kernel(const float* __restrict__ x,
                                                        float* __restrict__ xre,
                                                        float* __restrict__ xim) {
    __shared__ float lre[64 * 65];
    __shared__ float lim[64 * 65];
    __shared__ float twc[64];
    __shared__ float tws[64];
    const int t = threadIdx.x;
    const int j = blockIdx.x & 127;
    const int b = blockIdx.x >> 7;
    const int s1 = (j < 64) ? j : (384 + j);

    const float ang = (TWO_PI / 64.0f) * (float)t;
    twc[t] = cosf(ang);
    tws[t] = -sinf(ang);   // forward

    const float* __restrict__ src = x + ((size_t)(b * 512 + s1)) * 4096;
#pragma unroll
    for (int k = 0; k < 64; ++k) lre[k * 65 + t] = src[k * 64 + t];  // coalesced
    __syncthreads();

    float are[64], aim[64];
#pragma unroll
    for (int q = 0; q < 64; ++q) { are[q] = lre[t * 65 + bitrev6(q)]; aim[q] = 0.0f; }
    fft64_reg(are, aim, twc, tws);
#pragma unroll
    for (int q = 0; q < 64; ++q) { lre[t * 65 + q] = are[q]; lim[t * 65 + q] = aim[q]; }
    __syncthreads();

#pragma unroll
    for (int q = 0; q < 64; ++q) {
        const int r = bitrev6(q);
        are[q] = lre[r * 65 + t];
        aim[q] = lim[r * 65 + t];
    }
    fft64_reg(are, aim, twc, tws);

    float* __restrict__ dre = xre + (size_t)(j * 16 + b) * 4096;
    float* __restrict__ dim_ = xim + (size_t)(j * 16 + b) * 4096;
#pragma unroll
    for (int kp = 0; kp < 64; ++kp) {
        dre[kp * 64 + t] = are[kp];
        dim_[kp * 64 + t] = aim[kp];
    }
}

// ---------------- channel mix: X-in-LDS batched GEMM ----------------
// 1D grid 1024, XCD-chunked swizzle: the 8 o-half blocks of one (kx,set)
// share one XCD -> their common X slice (512 KB) lives in that XCD's L2.
// Block: 16 b x 8 o x 64 ky x 64 i.  Thread: kyq=t&15, u=t>>4: bp=u>>1
// (b=2bp+bb), op=u&1 (o=o0+op*4+oo).  acc = 2b x 4o x f4 x {re,im} = 64 VGPR.
// X double-buffered in LDS (IC=2 i-steps/chunk, 32 KB); W streamed to regs.
#define IC 2
#define NCH 32

__device__ __forceinline__ void fma4(float4& a, const float4& x, const float4& w) {
    a.x += x.x * w.x; a.y += x.y * w.y; a.z += x.z * w.z; a.w += x.w * w.w;
}

__device__ __forceinline__ void gl_lds16(const void* g, void* l) {
    __builtin_amdgcn_global_load_lds((const __attribute__((address_space(1))) void*)g,
                                     (__attribute__((address_space(3))) void*)l, 16, 0, 0);
}

// Stage chunk C into buffer SB: 32 (i,b)-rows of 256B each; each wave-load
// covers 4 consecutive rows (uniform LDS dest, lanes = rows x kyq).
#define STAGE(SB, C) do {                                                         \
    _Pragma("unroll")                                                             \
    for (int j_ = 0; j_ < 2; ++j_) {                                              \
        const int p0_ = (wv * 2 + j_) * 4;                                        \
        const int ii_ = p0_ >> 4;                                                 \
        const int b0_ = p0_ & 15;                                                 \
        const size_t go_ = ((size_t)(((C) * IC + ii_) * 16 + b0_ + sp_sub)) * 4096 \
                           + (size_t)s_kyq * 4;                                   \
        gl_lds16(xrB + go_, &sXr[SB][ii_][b0_ * 16]);                             \
        gl_lds16(xiB + go_, &sXi[SB][ii_][b0_ * 16]);                             \
    }                                                                             \
} while (0)

__global__ __launch_bounds__(256, 4) void mix_kernel(const float* __restrict__ xre,
                                                     const float* __restrict__ xim,
                                                     const float* __restrict__ w1,
                                                     const float* __restrict__ w2,
                                                     float* __restrict__ ore,
                                                     float* __restrict__ oim) {
    __shared__ float4 sXr[2][IC][256];   // [buf][ii][b*16 + kyq]  16 KB
    __shared__ float4 sXi[2][IC][256];   // 16 KB

    const int t = threadIdx.x;
    const int kyq = t & 15;
    const int u = t >> 4;
    const int bp = u >> 1;          // b = 2*bp + bb
    const int op = u & 1;           // o = o0 + op*4 + oo
    const int wv = t >> 6;
    const int l = t & 63;
    const int sp_sub = l >> 4;      // staging: row within wave-load
    const int s_kyq = l & 15;       // staging: ky quad

    // XCD-chunked swizzle (1024 = 8 XCD chunks x 128): all 8 o-half blocks
    // of one (kx,set) land in one chunk -> one XCD.
    const int phys = blockIdx.x;
    const int L = (phys & 7) * 128 + (phys >> 3);
    const int oh = L & 7;
    const int ksg = L >> 3;          // 0..127
    const int kx = ksg & 63;
    const int set = ksg >> 6;

    const int o0 = oh * 8;
    const float* __restrict__ w = set ? w2 : w1;
    const int fx = kx * 64;

    const float* __restrict__ xrB = xre + (size_t)(set * 64 * 16) * 4096 + fx;
    const float* __restrict__ xiB = xim + (size_t)(set * 64 * 16) * 4096 + fx;
    const float* __restrict__ wB  = w + fx;

    float4 accRe[2][4] = {};
    float4 accIm[2][4] = {};

    STAGE(0, 0);
    __syncthreads();

    int buf = 0;
#pragma unroll 1
    for (int c = 0; c < NCH; ++c) {
        if (c + 1 < NCH) STAGE(buf ^ 1, c + 1);
#pragma unroll
        for (int ii = 0; ii < IC; ++ii) {
            const int i = c * IC + ii;
            const float4 xr0 = sXr[buf][ii][(bp * 2 + 0) * 16 + kyq];
            const float4 xr1 = sXr[buf][ii][(bp * 2 + 1) * 16 + kyq];
            const float4 xi0 = sXi[buf][ii][(bp * 2 + 0) * 16 + kyq];
            const float4 xi1 = sXi[buf][ii][(bp * 2 + 1) * 16 + kyq];
            const float* __restrict__ wp = wB + (size_t)(i * 64 + o0 + op * 4) * 4096 + kyq * 4;
            float4 wq0 = *(const float4*)(wp);
            float4 wq1 = *(const float4*)(wp + 4096);
            float4 wq2 = *(const float4*)(wp + 2 * 4096);
            float4 wq3 = *(const float4*)(wp + 3 * 4096);
            fma4(accRe[0][0], xr0, wq0); fma4(accRe[0][1], xr0, wq1);
            fma4(accRe[0][2], xr0, wq2); fma4(accRe[0][3], xr0, wq3);
            fma4(accRe[1][0], xr1, wq0); fma4(accRe[1][1], xr1, wq1);
            fma4(accRe[1][2], xr1, wq2); fma4(accRe[1][3], xr1, wq3);
            fma4(accIm[0][0], xi0, wq0); fma4(accIm[0][1], xi0, wq1);
            fma4(accIm[0][2], xi0, wq2); fma4(accIm[0][3], xi0, wq3);
            fma4(accIm[1][0], xi1, wq0); fma4(accIm[1][1], xi1, wq1);
            fma4(accIm[1][2], xi1, wq2); fma4(accIm[1][3], xi1, wq3);
        }
        __syncthreads();
        buf ^= 1;
    }

#pragma unroll
    for (int bb = 0; bb < 2; ++bb)
#pragma unroll
        for (int oo = 0; oo < 4; ++oo) {
            const size_t pl = (size_t)set * 1024 + (size_t)(bp * 2 + bb) * 64 + (o0 + op * 4 + oo);
            const size_t q = (pl << 12) + fx + kyq * 4;
            *(float4*)(ore + q) = accRe[bb][oo];
            *(float4*)(oim + q) = accIm[bb][oo];
        }
}

// ---------------- inverse: 2D IFFT (complex->real) of 64x64 plane ----------------
__global__ __launch_bounds__(64, 1) void inv_fft_kernel(const float* __restrict__ ore,
                                                        const float* __restrict__ oim,
                                                        float* __restrict__ out) {
    __shared__ float lre[64 * 65];
    __shared__ float lim[64 * 65];
    __shared__ float twc[64];
    __shared__ float tws[64];
    const int t = threadIdx.x;
    const int pl = blockIdx.x;
    const int set = pl >> 10;
    const int b = (pl >> 6) & 15;
    const int o = pl & 63;

    const float ang = (TWO_PI / 64.0f) * (float)t;
    twc[t] = cosf(ang);
    tws[t] = sinf(ang);    // inverse

    const float* __restrict__ sre = ore + (size_t)pl * 4096;
    const float* __restrict__ sim = oim + (size_t)pl * 4096;
#pragma unroll
    for (int k = 0; k < 64; ++k) {
        lre[k * 65 + t] = sre[k * 64 + t];
        lim[k * 65 + t] = sim[k * 64 + t];
    }
    __syncthreads();

    float are[64], aim[64];
#pragma unroll
    for (int q = 0; q < 64; ++q) {
        const int r = bitrev6(q);
        are[q] = lre[t * 65 + r];
        aim[q] = lim[t * 65 + r];
    }
    fft64_reg(are, aim, twc, tws);
#pragma unroll
    for (int q = 0; q < 64; ++q) { lre[t * 65 + q] = are[q]; lim[t * 65 + q] = aim[q]; }
    __syncthreads();

#pragma unroll
    for (int q = 0; q < 64; ++q) {
        const int r = bitrev6(q);
        are[q] = lre[r * 65 + t];
        aim[q] = lim[r * 65 + t];
    }
    fft64_reg(are, aim, twc, tws);

    const int s1 = set ? (448 + o) : o;
    float* __restrict__ dst = out + ((size_t)(b * 512 + s1)) * 4096;
#pragma unroll
    for (int p = 0; p < 64; ++p)
        dst[p * 64 + t] = are[p] * (1.0f / 4096.0f);
}

// ---------------- zero-fill out[:, 64:448, :, :] ----------------
__global__ void zero_mid_kernel(float4* __restrict__ out) {
    const size_t per_b = (size_t)384 * 1024;  // float4 per batch mid-region
    const size_t i = (size_t)blockIdx.x * blockDim.x + threadIdx.x;
    if (i >= 16 * per_b) return;
    const size_t b = i / per_b;
    const size_t r = i - b * per_b;
    out[b * (512 * 1024) + 64 * 1024 + r] = make_float4(0.f, 0.f, 0.f, 0.f);
}

extern "C" void kernel_launch(void* const* d_in, const int* in_sizes, int n_in,
                              void* d_out, int out_size, void* d_ws, size_t ws_size,
                              hipStream_t stream) {
    const float* x  = (const float*)d_in[0];
    const float* w1 = (const float*)d_in[1];
    const float* w2 = (const float*)d_in[2];
    float* out = (float*)d_out;

    const size_t PLANE_FLOATS = (size_t)2048 * 4096;  // 33.5 MB each
    float* xre = (float*)d_ws;
    float* xim = xre + PLANE_FLOATS;
    float* ore = xim + PLANE_FLOATS;
    float* oim = ore + PLANE_FLOATS;
    // requires ws_size >= 134 MB

    fwd_fft_kernel<<<2048, 64, 0, stream>>>(x, xre, xim);
    mix_kernel<<<1024, 256, 0, stream>>>(xre, xim, w1, w2, ore, oim);
    inv_fft_kernel<<<2048, 64, 0, stream>>>(ore, oim, out);

    const int zthreads = 256;
    const int zblocks = (int)(((size_t)16 * 384 * 1024 + zthreads - 1) / zthreads);
    zero_mid_kernel<<<zblocks, zthreads, 0, stream>>>((float4*)out);
}

// Round 7
// 169.350 us; speedup vs baseline: 2.5366x; 1.2640x over previous
//
#include <hip/hip_runtime.h>
#include <cstdint>
#include <cstddef>

// SpectralConv2d: out = real(ifft2(concat[einsum(fft2(x)[:, :64], w1),
//                                         zeros, einsum(fft2(x)[:, -64:], w2)]))
// B=16, S1=512, S2=64, M2=64, in=out=m1=m2=64.
//
// ws layout (needs 134 MB):
//   XFT_re [128j][16b][64kx][64ky] fp32   (33.5 MB)   j<64 -> s1=j ; j>=64 -> s1=384+j
//   XFT_im                                 (33.5 MB)
//   OFT_re [2set][16b][64o][64kx][64ky]    (33.5 MB)
//   OFT_im                                 (33.5 MB)

#define TWO_PI 6.283185307179586f

__device__ __forceinline__ constexpr int bitrev6(int x) {
    return ((x & 1) << 5) | ((x & 2) << 3) | ((x & 4) << 1) |
           ((x & 8) >> 1) | ((x & 16) >> 3) | ((x & 32) >> 5);
}

// In-register 64-point FFT, input already bit-reversed, output natural order.
__device__ __forceinline__ void fft64_reg(float* re, float* im,
                                          const float* twc, const float* tws) {
#pragma unroll
    for (int s = 1; s <= 6; ++s) {
        const int m = 1 << s;
        const int h = m >> 1;
        const int step = 64 >> s;
#pragma unroll
        for (int k = 0; k < 64; k += m) {
#pragma unroll
            for (int j = 0; j < h; ++j) {
                const float wr = twc[j * step];
                const float wi = tws[j * step];
                const int p = k + j, q = p + h;
                const float tr = re[q] * wr - im[q] * wi;
                const float ti = re[q] * wi + im[q] * wr;
                re[q] = re[p] - tr; im[q] = im[p] - ti;
                re[p] = re[p] + tr; im[p] = im[p] + ti;
            }
        }
    }
}

// ---------------- forward: 2D FFT of 64x64 real tile ----------------
__global__ __launch_bounds__(64, 1) void fwd_fft_kernel(const float* __restrict__ x,
                                                        float* __restrict__ xre,
                                                        float* __restrict__ xim) {
    __shared__ float lre[64 * 65];
    __shared__ float lim[64 * 65];
    __shared__ float twc[64];
    __shared__ float tws[64];
    const int t = threadIdx.x;
    const int j = blockIdx.x & 127;
    const int b = blockIdx.x >> 7;
    const int s1 = (j < 64) ? j : (384 + j);

    const float ang = (TWO_PI / 64.0f) * (float)t;
    twc[t] = cosf(ang);
    tws[t] = -sinf(ang);   // forward

    const float* __restrict__ src = x + ((size_t)(b * 512 + s1)) * 4096;
#pragma unroll
    for (int k = 0; k < 64; ++k) lre[k * 65 + t] = src[k * 64 + t];  // coalesced
    __syncthreads();

    float are[64], aim[64];
#pragma unroll
    for (int q = 0; q < 64; ++q) { are[q] = lre[t * 65 + bitrev6(q)]; aim[q] = 0.0f; }
    fft64_reg(are, aim, twc, tws);
#pragma unroll
    for (int q = 0; q < 64; ++q) { lre[t * 65 + q] = are[q]; lim[t * 65 + q] = aim[q]; }
    __syncthreads();

#pragma unroll
    for (int q = 0; q < 64; ++q) {
        const int r = bitrev6(q);
        are[q] = lre[r * 65 + t];
        aim[q] = lim[r * 65 + t];
    }
    fft64_reg(are, aim, twc, tws);

    float* __restrict__ dre = xre + (size_t)(j * 16 + b) * 4096;
    float* __restrict__ dim_ = xim + (size_t)(j * 16 + b) * 4096;
#pragma unroll
    for (int kp = 0; kp < 64; ++kp) {
        dre[kp * 64 + t] = are[kp];
        dim_[kp * 64 + t] = aim[kp];
    }
}

// ---------------- channel mix: X+W both in LDS, batched GEMM ----------------
// 1D grid 1024, XCD-chunked swizzle: the 8 o-half blocks of one (kx,set)
// share one XCD -> their common X slice (512 KB) lives in that XCD's L2.
// Block: 16 b x 8 o x 64 ky x 64 i.  Thread: kyq=t&15, u=t>>4: bp=u>>1
// (b=2bp+bb), op=u&1 (o=o0+op*4+oo).  acc = 2b x 4o x f4 x {re,im} = 64 VGPR.
// X and W double-buffered in LDS (IC=2, 40 KB/block -> 4 blocks = 160 KB/CU);
// compute phase touches ONLY LDS; 20 gl_lds wave-loads/chunk prefetch c+1.
#define IC 2
#define NCH 32

__device__ __forceinline__ void fma4(float4& a, const float4& x, const float4& w) {
    a.x += x.x * w.x; a.y += x.y * w.y; a.z += x.z * w.z; a.w += x.w * w.w;
}

__device__ __forceinline__ void gl_lds16(const void* g, void* l) {
    __builtin_amdgcn_global_load_lds((const __attribute__((address_space(1))) void*)g,
                                     (__attribute__((address_space(3))) void*)l, 16, 0, 0);
}

// Stage chunk C into buffer SB.
// X: 32 rows (i,b)x(re,im) of 256B -> 16 wave-loads (4 rows each, 4/wave).
// W: 16 rows (i,o) of 256B -> 4 wave-loads (1/wave).
// Lanes: sp_sub = row-within-load (l>>4), s_kyq = float4 within row (l&15).
#define STAGE(SB, C) do {                                                          \
    _Pragma("unroll")                                                              \
    for (int j_ = 0; j_ < 2; ++j_) {                                               \
        const int p0_ = (wv * 2 + j_) * 4;                                         \
        const int ii_ = p0_ >> 4;                                                  \
        const int b0_ = p0_ & 15;                                                  \
        const size_t go_ = ((size_t)(((C) * IC + ii_) * 16 + b0_ + sp_sub)) * 4096 \
                           + (size_t)s_kyq * 4;                                    \
        gl_lds16(xrB + go_, &sXr[SB][ii_][b0_ * 16]);                              \
        gl_lds16(xiB + go_, &sXi[SB][ii_][b0_ * 16]);                              \
    }                                                                              \
    {                                                                              \
        const int wii_ = wv >> 1;                                                  \
        const int wo_ = (wv & 1) * 4;                                              \
        const size_t wgo_ = ((size_t)(((C) * IC + wii_) * 64 + o0 + wo_ + sp_sub)) \
                            * 4096 + (size_t)s_kyq * 4;                            \
        gl_lds16(wB + wgo_, &sW[SB][wii_][wo_ * 16]);                              \
    }                                                                              \
} while (0)

__global__ __launch_bounds__(256, 4) void mix_kernel(const float* __restrict__ xre,
                                                     const float* __restrict__ xim,
                                                     const float* __restrict__ w1,
                                                     const float* __restrict__ w2,
                                                     float* __restrict__ ore,
                                                     float* __restrict__ oim) {
    __shared__ float4 sXr[2][IC][256];   // [buf][ii][b*16 + kyq]   16 KB
    __shared__ float4 sXi[2][IC][256];   //                          16 KB
    __shared__ float4 sW[2][IC][128];    // [buf][ii][o*16 + kyq]     8 KB

    const int t = threadIdx.x;
    const int kyq = t & 15;
    const int u = t >> 4;
    const int bp = u >> 1;          // b = 2*bp + bb
    const int op = u & 1;           // o = o0 + op*4 + oo
    const int wv = t >> 6;
    const int l = t & 63;
    const int sp_sub = l >> 4;      // staging: row within wave-load
    const int s_kyq = l & 15;       // staging: float4 within row

    // XCD-chunked swizzle (1024 = 8 XCD chunks x 128): all 8 o-half blocks
    // of one (kx,set) land in one chunk -> one XCD.
    const int phys = blockIdx.x;
    const int L = (phys & 7) * 128 + (phys >> 3);
    const int oh = L & 7;
    const int ksg = L >> 3;          // 0..127
    const int kx = ksg & 63;
    const int set = ksg >> 6;

    const int o0 = oh * 8;
    const float* __restrict__ w = set ? w2 : w1;
    const int fx = kx * 64;

    const float* __restrict__ xrB = xre + (size_t)(set * 64 * 16) * 4096 + fx;
    const float* __restrict__ xiB = xim + (size_t)(set * 64 * 16) * 4096 + fx;
    const float* __restrict__ wB  = w + fx;

    float4 accRe[2][4] = {};
    float4 accIm[2][4] = {};

    STAGE(0, 0);
    __syncthreads();

    int buf = 0;
#pragma unroll 1
    for (int c = 0; c < NCH; ++c) {
        if (c + 1 < NCH) STAGE(buf ^ 1, c + 1);
#pragma unroll
        for (int ii = 0; ii < IC; ++ii) {
            const float4 xr0 = sXr[buf][ii][(bp * 2 + 0) * 16 + kyq];
            const float4 xr1 = sXr[buf][ii][(bp * 2 + 1) * 16 + kyq];
            const float4 xi0 = sXi[buf][ii][(bp * 2 + 0) * 16 + kyq];
            const float4 xi1 = sXi[buf][ii][(bp * 2 + 1) * 16 + kyq];
            const float4 wq0 = sW[buf][ii][(op * 4 + 0) * 16 + kyq];
            const float4 wq1 = sW[buf][ii][(op * 4 + 1) * 16 + kyq];
            const float4 wq2 = sW[buf][ii][(op * 4 + 2) * 16 + kyq];
            const float4 wq3 = sW[buf][ii][(op * 4 + 3) * 16 + kyq];
            fma4(accRe[0][0], xr0, wq0); fma4(accRe[0][1], xr0, wq1);
            fma4(accRe[0][2], xr0, wq2); fma4(accRe[0][3], xr0, wq3);
            fma4(accRe[1][0], xr1, wq0); fma4(accRe[1][1], xr1, wq1);
            fma4(accRe[1][2], xr1, wq2); fma4(accRe[1][3], xr1, wq3);
            fma4(accIm[0][0], xi0, wq0); fma4(accIm[0][1], xi0, wq1);
            fma4(accIm[0][2], xi0, wq2); fma4(accIm[0][3], xi0, wq3);
            fma4(accIm[1][0], xi1, wq0); fma4(accIm[1][1], xi1, wq1);
            fma4(accIm[1][2], xi1, wq2); fma4(accIm[1][3], xi1, wq3);
        }
        __syncthreads();
        buf ^= 1;
    }

#pragma unroll
    for (int bb = 0; bb < 2; ++bb)
#pragma unroll
        for (int oo = 0; oo < 4; ++oo) {
            const size_t pl = (size_t)set * 1024 + (size_t)(bp * 2 + bb) * 64 + (o0 + op * 4 + oo);
            const size_t q = (pl << 12) + fx + kyq * 4;
            *(float4*)(ore + q) = accRe[bb][oo];
            *(float4*)(oim + q) = accIm[bb][oo];
        }
}

// ---------------- inverse: 2D IFFT (complex->real) of 64x64 plane ----------------
__global__ __launch_bounds__(64, 1) void inv_fft_kernel(const float* __restrict__ ore,
                                                        const float* __restrict__ oim,
                                                        float* __restrict__ out) {
    __shared__ float lre[64 * 65];
    __shared__ float lim[64 * 65];
    __shared__ float twc[64];
    __shared__ float tws[64];
    const int t = threadIdx.x;
    const int pl = blockIdx.x;
    const int set = pl >> 10;
    const int b = (pl >> 6) & 15;
    const int o = pl & 63;

    const float ang = (TWO_PI / 64.0f) * (float)t;
    twc[t] = cosf(ang);
    tws[t] = sinf(ang);    // inverse

    const float* __restrict__ sre = ore + (size_t)pl * 4096;
    const float* __restrict__ sim = oim + (size_t)pl * 4096;
#pragma unroll
    for (int k = 0; k < 64; ++k) {
        lre[k * 65 + t] = sre[k * 64 + t];
        lim[k * 65 + t] = sim[k * 64 + t];
    }
    __syncthreads();

    float are[64], aim[64];
#pragma unroll
    for (int q = 0; q < 64; ++q) {
        const int r = bitrev6(q);
        are[q] = lre[t * 65 + r];
        aim[q] = lim[t * 65 + r];
    }
    fft64_reg(are, aim, twc, tws);
#pragma unroll
    for (int q = 0; q < 64; ++q) { lre[t * 65 + q] = are[q]; lim[t * 65 + q] = aim[q]; }
    __syncthreads();

#pragma unroll
    for (int q = 0; q < 64; ++q) {
        const int r = bitrev6(q);
        are[q] = lre[r * 65 + t];
        aim[q] = lim[r * 65 + t];
    }
    fft64_reg(are, aim, twc, tws);

    const int s1 = set ? (448 + o) : o;
    float* __restrict__ dst = out + ((size_t)(b * 512 + s1)) * 4096;
#pragma unroll
    for (int p = 0; p < 64; ++p)
        dst[p * 64 + t] = are[p] * (1.0f / 4096.0f);
}

// ---------------- zero-fill out[:, 64:448, :, :] ----------------
__global__ void zero_mid_kernel(float4* __restrict__ out) {
    const size_t per_b = (size_t)384 * 1024;  // float4 per batch mid-region
    const size_t i = (size_t)blockIdx.x * blockDim.x + threadIdx.x;
    if (i >= 16 * per_b) return;
    const size_t b = i / per_b;
    const size_t r = i - b * per_b;
    out[b * (512 * 1024) + 64 * 1024 + r] = make_float4(0.f, 0.f, 0.f, 0.f);
}

extern "C" void kernel_launch(void* const* d_in, const int* in_sizes, int n_in,
                              void* d_out, int out_size, void* d_ws, size_t ws_size,
                              hipStream_t stream) {
    const float* x  = (const float*)d_in[0];
    const float* w1 = (const float*)d_in[1];
    const float* w2 = (const float*)d_in[2];
    float* out = (float*)d_out;

    const size_t PLANE_FLOATS = (size_t)2048 * 4096;  // 33.5 MB each
    float* xre = (float*)d_ws;
    float* xim = xre + PLANE_FLOATS;
    float* ore = xim + PLANE_FLOATS;
    float* oim = ore + PLANE_FLOATS;
    // requires ws_size >= 134 MB

    fwd_fft_kernel<<<2048, 64, 0, stream>>>(x, xre, xim);
    mix_kernel<<<1024, 256, 0, stream>>>(xre, xim, w1, w2, ore, oim);
    inv_fft_kernel<<<2048, 64, 0, stream>>>(ore, oim, out);

    const int zthreads = 256;
    const int zblocks = (int)(((size_t)16 * 384 * 1024 + zthreads - 1) / zthreads);
    zero_mid_kernel<<<zblocks, zthreads, 0, stream>>>((float4*)out);
}

// Round 8
// 168.657 us; speedup vs baseline: 2.5470x; 1.0041x over previous
//
#include <hip/hip_runtime.h>
#include <cstdint>
#include <cstddef>

// SpectralConv2d: out = real(ifft2(concat[einsum(fft2(x)[:, :64], w1),
//                                         zeros, einsum(fft2(x)[:, -64:], w2)]))
// B=16, S1=512, S2=64, M2=64, in=out=m1=m2=64.
//
// ws layout (~101 MB):
//   XFT_re f16 [128j][16b][64kx][64ky]   (16.8 MB)   j<64 -> s1=j ; j>=64 -> s1=384+j
//   XFT_im f16                            (16.8 MB)
//   OFT_re f32 [2set*16b*64o][64kx][64ky] (33.5 MB)
//   OFT_im f32                            (33.5 MB)

#define TWO_PI 6.283185307179586f

typedef _Float16 f16;
typedef _Float16 f16x8 __attribute__((ext_vector_type(8)));
typedef float f32x4 __attribute__((ext_vector_type(4)));

__device__ __forceinline__ constexpr int bitrev6(int x) {
    return ((x & 1) << 5) | ((x & 2) << 3) | ((x & 4) << 1) |
           ((x & 8) >> 1) | ((x & 16) >> 3) | ((x & 32) >> 5);
}

// In-register 64-point FFT, input already bit-reversed, output natural order.
__device__ __forceinline__ void fft64_reg(float* re, float* im,
                                          const float* twc, const float* tws) {
#pragma unroll
    for (int s = 1; s <= 6; ++s) {
        const int m = 1 << s;
        const int h = m >> 1;
        const int step = 64 >> s;
#pragma unroll
        for (int k = 0; k < 64; k += m) {
#pragma unroll
            for (int j = 0; j < h; ++j) {
                const float wr = twc[j * step];
                const float wi = tws[j * step];
                const int p = k + j, q = p + h;
                const float tr = re[q] * wr - im[q] * wi;
                const float ti = re[q] * wi + im[q] * wr;
                re[q] = re[p] - tr; im[q] = im[p] - ti;
                re[p] = re[p] + tr; im[p] = im[p] + ti;
            }
        }
    }
}

// ---------------- forward: 2D FFT of 64x64 real tile -> f16 planes ----------------
__global__ __launch_bounds__(64, 1) void fwd_fft_kernel(const float* __restrict__ x,
                                                        f16* __restrict__ xre,
                                                        f16* __restrict__ xim) {
    __shared__ float lre[64 * 65];
    __shared__ float lim[64 * 65];
    __shared__ float twc[64];
    __shared__ float tws[64];
    const int t = threadIdx.x;
    const int j = blockIdx.x & 127;
    const int b = blockIdx.x >> 7;
    const int s1 = (j < 64) ? j : (384 + j);

    const float ang = (TWO_PI / 64.0f) * (float)t;
    twc[t] = cosf(ang);
    tws[t] = -sinf(ang);   // forward

    const float* __restrict__ src = x + ((size_t)(b * 512 + s1)) * 4096;
#pragma unroll
    for (int k = 0; k < 64; ++k) lre[k * 65 + t] = src[k * 64 + t];  // coalesced
    __syncthreads();

    float are[64], aim[64];
#pragma unroll
    for (int q = 0; q < 64; ++q) { are[q] = lre[t * 65 + bitrev6(q)]; aim[q] = 0.0f; }
    fft64_reg(are, aim, twc, tws);
#pragma unroll
    for (int q = 0; q < 64; ++q) { lre[t * 65 + q] = are[q]; lim[t * 65 + q] = aim[q]; }
    __syncthreads();

#pragma unroll
    for (int q = 0; q < 64; ++q) {
        const int r = bitrev6(q);
        are[q] = lre[r * 65 + t];
        aim[q] = lim[r * 65 + t];
    }
    fft64_reg(are, aim, twc, tws);

    f16* __restrict__ dre = xre + (size_t)(j * 16 + b) * 4096;
    f16* __restrict__ dim_ = xim + (size_t)(j * 16 + b) * 4096;
#pragma unroll
    for (int kp = 0; kp < 64; ++kp) {      // lanes = ky -> 128B contiguous per instr
        dre[kp * 64 + t] = (f16)are[kp];
        dim_[kp * 64 + t] = (f16)aim[kp];
    }
}

// ---------------- channel mix: MFMA batched GEMM per (kx,ky,set) ----------------
// Per point: C[16b][64o] = A[16b][64i] * B[64i][64o], B real (shared re/im).
// Block = (kx, ky-oct, set): 1024 blocks, 256 thr (4 waves, wave = 2 ky-points).
// A-frags preloaded to regs via LDS slot-order bounce; W streamed through
// double-buffered LDS in 8 chunks (oc x ic), T14 split (load early, cvt+write late).
// Frag LDS layout = lane*16B slot order -> conflict-free ds_read_b128.
// W scaled by 2^14 at cvt (exact), undone at flush (avoids f16 subnormal flush).
#define WSCALE 16384.0f
#define WINV   (1.0f / 16384.0f)

__global__ __launch_bounds__(256, 2) void mix_kernel(const f16* __restrict__ xre,
                                                     const f16* __restrict__ xim,
                                                     const float* __restrict__ w1,
                                                     const float* __restrict__ w2,
                                                     float* __restrict__ ore,
                                                     float* __restrict__ oim) {
    // sX: [8ky][2part][2ic][64slot][8j] f16 = 32 KB (A-frag slot order)
    // sW: [2buf][8ky][64slot][8j] f16   = 16 KB (B-frag slot order)
    // sC: [2part][16b][16o][8ky] f32    = 16 KB (flush staging)
    __shared__ f16 sX[16384];
    __shared__ f16 sW[8192];
    __shared__ float sC[4096];

    const int t = threadIdx.x;
    const int lane = t & 63;
    const int wv = t >> 6;

    // XCD-chunked swizzle; L-order: kyoct fastest, then kx, then set
    const int phys = blockIdx.x;
    const int L = (phys & 7) * 128 + (phys >> 3);
    const int set = L >> 9;
    const int kx = (L >> 3) & 63;
    const int kyoct = L & 7;
    const int ky0 = kyoct * 8;

    const float* __restrict__ w = set ? w2 : w1;
    const f16* __restrict__ xrB = xre + (size_t)(set * 64) * 16 * 4096;
    const f16* __restrict__ xiB = xim + (size_t)(set * 64) * 16 * 4096;

    // ---- X staging: global f16x8 (8 ky) per (i,b) -> slot-order scatter ----
#pragma unroll
    for (int part = 0; part < 2; ++part) {
        const f16* __restrict__ src = part ? xiB : xrB;
#pragma unroll
        for (int s = 0; s < 4; ++s) {
            const int flat = s * 256 + t;
            const int i = flat >> 4;          // 0..63
            const int b = flat & 15;
            f16x8 v = *(const f16x8*)(src + (size_t)(i * 16 + b) * 4096 + kx * 64 + ky0);
            const int eb = part * 1024 + (i >> 5) * 512 + (((i >> 3) & 3) * 16 + b) * 8 + (i & 7);
#pragma unroll
            for (int q = 0; q < 8; ++q) sX[q * 2048 + eb] = v[q];
        }
    }

    // ---- W chunk 0: load + cvt/write (prologue) ----
    float wl[16];
#define WLOAD(CH) do {                                                              \
    const int oc_ = (CH) >> 1, ic_ = (CH) & 1;                                      \
    _Pragma("unroll")                                                               \
    for (int s_ = 0; s_ < 4; ++s_) {                                                \
        const int st_ = s_ * 256 + t;                                               \
        const int i_ = st_ >> 5, o_ = (st_ >> 1) & 15, kh_ = st_ & 1;               \
        const float4 v_ = *(const float4*)(w +                                      \
            (size_t)((ic_ * 32 + i_) * 64 + (oc_ * 16 + o_)) * 4096                 \
            + kx * 64 + ky0 + kh_ * 4);                                             \
        wl[s_ * 4 + 0] = v_.x; wl[s_ * 4 + 1] = v_.y;                               \
        wl[s_ * 4 + 2] = v_.z; wl[s_ * 4 + 3] = v_.w;                               \
    }                                                                               \
} while (0)

#define WWRITE(BUF) do {                                                            \
    _Pragma("unroll")                                                               \
    for (int s_ = 0; s_ < 4; ++s_) {                                                \
        const int st_ = s_ * 256 + t;                                               \
        const int i_ = st_ >> 5, o_ = (st_ >> 1) & 15, kh_ = st_ & 1;               \
        const int eb_ = (BUF) * 4096 + ((i_ >> 3) * 16 + o_) * 8 + (i_ & 7);        \
        _Pragma("unroll")                                                           \
        for (int q_ = 0; q_ < 4; ++q_)                                              \
            sW[eb_ + (kh_ * 4 + q_) * 512] = (f16)(wl[s_ * 4 + q_] * WSCALE);       \
    }                                                                               \
} while (0)

    WLOAD(0);
    WWRITE(0);
    __syncthreads();

    // ---- A-frag preload: [pt][part][ic], conflict-free b128 ----
    f16x8 afrag[2][2][2];
#pragma unroll
    for (int pt = 0; pt < 2; ++pt)
#pragma unroll
        for (int part = 0; part < 2; ++part)
#pragma unroll
            for (int ic = 0; ic < 2; ++ic)
                afrag[pt][part][ic] = *(const f16x8*)(sX + (2 * wv + pt) * 2048
                                                      + part * 1024 + ic * 512 + lane * 8);

    f32x4 acc[2][2];   // [pt][part]
#pragma unroll
    for (int pt = 0; pt < 2; ++pt)
#pragma unroll
        for (int part = 0; part < 2; ++part)
#pragma unroll
            for (int q = 0; q < 4; ++q) acc[pt][part][q] = 0.0f;

#pragma unroll
    for (int c = 0; c < 8; ++c) {
        if (c + 1 < 8) WLOAD(c + 1);          // T14: issue next loads early
        const int buf = c & 1;
        const int ic = c & 1;
#pragma unroll
        for (int pt = 0; pt < 2; ++pt) {
            const f16x8 bfrag = *(const f16x8*)(sW + buf * 4096 + (2 * wv + pt) * 512 + lane * 8);
#pragma unroll
            for (int part = 0; part < 2; ++part)
                acc[pt][part] = __builtin_amdgcn_mfma_f32_16x16x32_f16(
                    afrag[pt][part][ic], bfrag, acc[pt][part], 0, 0, 0);
        }
        if (c + 1 < 8) WWRITE(buf ^ 1);       // cvt + LDS write after compute
        __syncthreads();

        if (ic == 1) {                        // end of o-chunk: flush C
            const int oc = c >> 1;
#pragma unroll
            for (int part = 0; part < 2; ++part)
#pragma unroll
                for (int r = 0; r < 4; ++r) {
                    const int b = (lane >> 4) * 4 + r;
                    const int o = lane & 15;
                    float2 v2 = make_float2(acc[0][part][r] * WINV, acc[1][part][r] * WINV);
                    *(float2*)(sC + part * 2048 + (b * 16 + o) * 8 + 2 * wv) = v2;
                }
            __syncthreads();
#pragma unroll
            for (int part = 0; part < 2; ++part) {
                float* __restrict__ dst = part ? oim : ore;
                const int r2 = wv * 64 + lane;         // 256 (b,o) runs, 4 waves x 64
                const int b = r2 >> 4, o = r2 & 15;
                const float4 lo = *(const float4*)(sC + part * 2048 + (b * 16 + o) * 8);
                const float4 hi = *(const float4*)(sC + part * 2048 + (b * 16 + o) * 8 + 4);
                float* gp = dst + (size_t)(set * 1024 + b * 64 + oc * 16 + o) * 4096
                            + kx * 64 + ky0;
                *(float4*)gp = lo;
                *(float4*)(gp + 4) = hi;
            }
            __syncthreads();
#pragma unroll
            for (int pt = 0; pt < 2; ++pt)
#pragma unroll
                for (int part = 0; part < 2; ++part)
#pragma unroll
                    for (int q = 0; q < 4; ++q) acc[pt][part][q] = 0.0f;
        }
    }
#undef WLOAD
#undef WWRITE
}

// ---------------- inverse: 2D IFFT (complex->real) of 64x64 plane ----------------
__global__ __launch_bounds__(64, 1) void inv_fft_kernel(const float* __restrict__ ore,
                                                        const float* __restrict__ oim,
                                                        float* __restrict__ out) {
    __shared__ float lre[64 * 65];
    __shared__ float lim[64 * 65];
    __shared__ float twc[64];
    __shared__ float tws[64];
    const int t = threadIdx.x;
    const int pl = blockIdx.x;
    const int set = pl >> 10;
    const int b = (pl >> 6) & 15;
    const int o = pl & 63;

    const float ang = (TWO_PI / 64.0f) * (float)t;
    twc[t] = cosf(ang);
    tws[t] = sinf(ang);    // inverse

    const float* __restrict__ sre = ore + (size_t)pl * 4096;
    const float* __restrict__ sim = oim + (size_t)pl * 4096;
#pragma unroll
    for (int k = 0; k < 64; ++k) {
        lre[k * 65 + t] = sre[k * 64 + t];
        lim[k * 65 + t] = sim[k * 64 + t];
    }
    __syncthreads();

    float are[64], aim[64];
#pragma unroll
    for (int q = 0; q < 64; ++q) {
        const int r = bitrev6(q);
        are[q] = lre[t * 65 + r];
        aim[q] = lim[t * 65 + r];
    }
    fft64_reg(are, aim, twc, tws);
#pragma unroll
    for (int q = 0; q < 64; ++q) { lre[t * 65 + q] = are[q]; lim[t * 65 + q] = aim[q]; }
    __syncthreads();

#pragma unroll
    for (int q = 0; q < 64; ++q) {
        const int r = bitrev6(q);
        are[q] = lre[r * 65 + t];
        aim[q] = lim[r * 65 + t];
    }
    fft64_reg(are, aim, twc, tws);

    const int s1 = set ? (448 + o) : o;
    float* __restrict__ dst = out + ((size_t)(b * 512 + s1)) * 4096;
#pragma unroll
    for (int p = 0; p < 64; ++p)
        dst[p * 64 + t] = are[p] * (1.0f / 4096.0f);
}

// ---------------- zero-fill out[:, 64:448, :, :] ----------------
__global__ void zero_mid_kernel(float4* __restrict__ out) {
    const size_t per_b = (size_t)384 * 1024;  // float4 per batch mid-region
    const size_t i = (size_t)blockIdx.x * blockDim.x + threadIdx.x;
    if (i >= 16 * per_b) return;
    const size_t b = i / per_b;
    const size_t r = i - b * per_b;
    out[b * (512 * 1024) + 64 * 1024 + r] = make_float4(0.f, 0.f, 0.f, 0.f);
}

extern "C" void kernel_launch(void* const* d_in, const int* in_sizes, int n_in,
                              void* d_out, int out_size, void* d_ws, size_t ws_size,
                              hipStream_t stream) {
    const float* x  = (const float*)d_in[0];
    const float* w1 = (const float*)d_in[1];
    const float* w2 = (const float*)d_in[2];
    float* out = (float*)d_out;

    const size_t PLANE = (size_t)2048 * 4096;   // elements per XFT/OFT tensor
    f16* xre16 = (f16*)d_ws;                    // 16.8 MB
    f16* xim16 = xre16 + PLANE;                 // 16.8 MB
    float* ore = (float*)(xim16 + PLANE);       // 33.5 MB
    float* oim = ore + PLANE;                   // 33.5 MB
    // requires ws_size >= ~101 MB

    fwd_fft_kernel<<<2048, 64, 0, stream>>>(x, xre16, xim16);
    mix_kernel<<<1024, 256, 0, stream>>>(xre16, xim16, w1, w2, ore, oim);
    inv_fft_kernel<<<2048, 64, 0, stream>>>(ore, oim, out);

    const int zthreads = 256;
    const int zblocks = (int)(((size_t)16 * 384 * 1024 + zthreads - 1) / zthreads);
    zero_mid_kernel<<<zblocks, zthreads, 0, stream>>>((float4*)out);
}

// Round 9
// 125.194 us; speedup vs baseline: 3.4313x; 1.3472x over previous
//
#include <hip/hip_runtime.h>
#include <cstdint>
#include <cstddef>

// SpectralConv2d: out = real(ifft2(concat[einsum(fft2(x)[:, :64], w1),
//                                         zeros, einsum(fft2(x)[:, -64:], w2)]))
// B=16, S1=512, S2=64, M2=64, in=out=m1=m2=64.
//
// ws layout (67 MB, all f16):
//   XFT_re [128j][16b][64kx][64ky] f16  (16.8 MB)  j<64 -> s1=j ; j>=64 -> s1=384+j
//   XFT_im  (= XFT_re + PLANE)           (16.8 MB)
//   OFT_re [2set*16b*64o][64kx][64ky]    (16.8 MB)
//   OFT_im  (= OFT_re + PLANE)           (16.8 MB)

#define TWO_PI 6.283185307179586f
#define PLANE_ELEMS ((size_t)2048 * 4096)

typedef _Float16 f16;
typedef _Float16 f16x4 __attribute__((ext_vector_type(4)));

__device__ __forceinline__ constexpr int bitrev6(int x) {
    return ((x & 1) << 5) | ((x & 2) << 3) | ((x & 4) << 1) |
           ((x & 8) >> 1) | ((x & 16) >> 3) | ((x & 32) >> 5);
}

// In-register 64-point FFT, input already bit-reversed, output natural order.
__device__ __forceinline__ void fft64_reg(float* re, float* im,
                                          const float* twc, const float* tws) {
#pragma unroll
    for (int s = 1; s <= 6; ++s) {
        const int m = 1 << s;
        const int h = m >> 1;
        const int step = 64 >> s;
#pragma unroll
        for (int k = 0; k < 64; k += m) {
#pragma unroll
            for (int j = 0; j < h; ++j) {
                const float wr = twc[j * step];
                const float wi = tws[j * step];
                const int p = k + j, q = p + h;
                const float tr = re[q] * wr - im[q] * wi;
                const float ti = re[q] * wi + im[q] * wr;
                re[q] = re[p] - tr; im[q] = im[p] - ti;
                re[p] = re[p] + tr; im[p] = im[p] + ti;
            }
        }
    }
}

// ---------------- forward: 2D FFT of 64x64 real tile -> f16 planes ----------------
__global__ __launch_bounds__(64, 1) void fwd_fft_kernel(const float* __restrict__ x,
                                                        f16* __restrict__ xre,
                                                        f16* __restrict__ xim) {
    __shared__ float lre[64 * 65];
    __shared__ float lim[64 * 65];
    __shared__ float twc[64];
    __shared__ float tws[64];
    const int t = threadIdx.x;
    const int j = blockIdx.x & 127;
    const int b = blockIdx.x >> 7;
    const int s1 = (j < 64) ? j : (384 + j);

    const float ang = (TWO_PI / 64.0f) * (float)t;
    twc[t] = cosf(ang);
    tws[t] = -sinf(ang);   // forward

    const float* __restrict__ src = x + ((size_t)(b * 512 + s1)) * 4096;
#pragma unroll
    for (int k = 0; k < 64; ++k) lre[k * 65 + t] = src[k * 64 + t];  // coalesced
    __syncthreads();

    float are[64], aim[64];
#pragma unroll
    for (int q = 0; q < 64; ++q) { are[q] = lre[t * 65 + bitrev6(q)]; aim[q] = 0.0f; }
    fft64_reg(are, aim, twc, tws);
#pragma unroll
    for (int q = 0; q < 64; ++q) { lre[t * 65 + q] = are[q]; lim[t * 65 + q] = aim[q]; }
    __syncthreads();

#pragma unroll
    for (int q = 0; q < 64; ++q) {
        const int r = bitrev6(q);
        are[q] = lre[r * 65 + t];
        aim[q] = lim[r * 65 + t];
    }
    fft64_reg(are, aim, twc, tws);

    f16* __restrict__ dre = xre + (size_t)(j * 16 + b) * 4096;
    f16* __restrict__ dim_ = xim + (size_t)(j * 16 + b) * 4096;
#pragma unroll
    for (int kp = 0; kp < 64; ++kp) {      // lanes = ky -> 128B contiguous/instr
        dre[kp * 64 + t] = (f16)are[kp];
        dim_[kp * 64 + t] = (f16)aim[kp];
    }
}

// ---------------- channel mix: X(f16)+W(f32) in LDS, f16 OFT out ----------------
// v8 skeleton (proven 98us): 1D grid 1024, XCD-chunked swizzle; block =
// (kx, o-oct, set): 16 b x 8 o x 64 ky x 64 i.  Thread: kyq=t&15, u=t>>4:
// bp=u>>1 (b=2bp+bb), op=u&1 (o=o0+op*4+oo).  acc = 2b x 4o x f4 x {re,im}
// = 64 VGPR.  Double-buffered LDS, IC=2 i/chunk, 24 KB/block -> 4 blocks/CU.
// X rows f16 [r=(ii*2+part)*16+b][64ky] (128B); W rows f32 [ii*8+o][64ky] (256B).
// Per chunk: 8 X wave-loads (2/wave) + 4 W wave-loads (1/wave) via gl_lds16.
#define IC 2
#define NCH 32

__device__ __forceinline__ void fma4(float4& a, const float4& x, const float4& w) {
    a.x += x.x * w.x; a.y += x.y * w.y; a.z += x.z * w.z; a.w += x.w * w.w;
}

__device__ __forceinline__ void gl_lds16(const void* g, void* l) {
    __builtin_amdgcn_global_load_lds((const __attribute__((address_space(1))) void*)g,
                                     (__attribute__((address_space(3))) void*)l, 16, 0, 0);
}

#define STAGE(SB, C) do {                                                          \
    const int i0_ = (C) * IC;                                                      \
    _Pragma("unroll")                                                              \
    for (int j_ = 0; j_ < 2; ++j_) {                                               \
        const int q_ = wv * 2 + j_;                                                \
        const int r_ = q_ * 8 + (l >> 3);                                          \
        const int ii_ = r_ >> 5;                                                   \
        const int part_ = (r_ >> 4) & 1;                                           \
        const int b_ = r_ & 15;                                                    \
        const f16* g_ = xB + (size_t)part_ * PLANE_ELEMS                           \
                        + (size_t)((i0_ + ii_) * 16 + b_) * 4096 + (l & 7) * 8;    \
        gl_lds16(g_, &sX[SB][q_ * 512]);                                           \
    }                                                                              \
    {                                                                              \
        const int r_ = wv * 4 + (l >> 4);                                          \
        const int ii_ = r_ >> 3;                                                   \
        const int o_ = r_ & 7;                                                     \
        const float* g_ = wB + (size_t)((i0_ + ii_) * 64 + o0 + o_) * 4096         \
                          + (l & 15) * 4;                                          \
        gl_lds16(g_, &sW[SB][wv * 256]);                                           \
    }                                                                              \
} while (0)

__global__ __launch_bounds__(256, 4) void mix_kernel(const f16* __restrict__ xft,
                                                     const float* __restrict__ w1,
                                                     const float* __restrict__ w2,
                                                     f16* __restrict__ oft) {
    __shared__ f16  sX[2][4096];   // 8 KB/buf: [row r=(ii*2+part)*16+b][64ky]
    __shared__ float sW[2][1024];  // 4 KB/buf: [row ii*8+o][64ky]

    const int t = threadIdx.x;
    const int kyq = t & 15;
    const int u = t >> 4;
    const int bp = u >> 1;          // b = 2*bp + bb
    const int op = u & 1;           // o = o0 + op*4 + oo
    const int wv = t >> 6;
    const int l = t & 63;

    // XCD-chunked swizzle: all 8 o-oct blocks of one (kx,set) -> one XCD chunk.
    const int phys = blockIdx.x;
    const int L = (phys & 7) * 128 + (phys >> 3);
    const int oh = L & 7;
    const int ksg = L >> 3;
    const int kx = ksg & 63;
    const int set = ksg >> 6;
    const int o0 = oh * 8;

    const float* __restrict__ w = set ? w2 : w1;
    const f16* __restrict__ xB = xft + (size_t)(set * 64 * 16) * 4096 + kx * 64;
    const float* __restrict__ wB = w + kx * 64;

    float4 accRe[2][4] = {};
    float4 accIm[2][4] = {};

    STAGE(0, 0);
    __syncthreads();

    int buf = 0;
#pragma unroll 1
    for (int c = 0; c < NCH; ++c) {
        if (c + 1 < NCH) STAGE(buf ^ 1, c + 1);
#pragma unroll
        for (int ii = 0; ii < IC; ++ii) {
            float4 xr[2], xi[2];
#pragma unroll
            for (int bb = 0; bb < 2; ++bb) {
                const f16x4 hr = *(const f16x4*)(&sX[buf][(((ii * 2 + 0) * 16) + bp * 2 + bb) * 64 + kyq * 4]);
                const f16x4 hi = *(const f16x4*)(&sX[buf][(((ii * 2 + 1) * 16) + bp * 2 + bb) * 64 + kyq * 4]);
                xr[bb] = make_float4((float)hr[0], (float)hr[1], (float)hr[2], (float)hr[3]);
                xi[bb] = make_float4((float)hi[0], (float)hi[1], (float)hi[2], (float)hi[3]);
            }
            float4 wq[4];
#pragma unroll
            for (int oo = 0; oo < 4; ++oo)
                wq[oo] = *(const float4*)(&sW[buf][(ii * 8 + op * 4 + oo) * 64 + kyq * 4]);
#pragma unroll
            for (int oo = 0; oo < 4; ++oo) {
                fma4(accRe[0][oo], xr[0], wq[oo]);
                fma4(accRe[1][oo], xr[1], wq[oo]);
                fma4(accIm[0][oo], xi[0], wq[oo]);
                fma4(accIm[1][oo], xi[1], wq[oo]);
            }
        }
        __syncthreads();
        buf ^= 1;
    }

#pragma unroll
    for (int bb = 0; bb < 2; ++bb)
#pragma unroll
        for (int oo = 0; oo < 4; ++oo) {
            const size_t pl = (size_t)set * 1024 + (size_t)(bp * 2 + bb) * 64 + (o0 + op * 4 + oo);
            f16x4 vr, vi;
            vr[0] = (f16)accRe[bb][oo].x; vr[1] = (f16)accRe[bb][oo].y;
            vr[2] = (f16)accRe[bb][oo].z; vr[3] = (f16)accRe[bb][oo].w;
            vi[0] = (f16)accIm[bb][oo].x; vi[1] = (f16)accIm[bb][oo].y;
            vi[2] = (f16)accIm[bb][oo].z; vi[3] = (f16)accIm[bb][oo].w;
            f16* gp = oft + pl * 4096 + kx * 64 + kyq * 4;
            *(f16x4*)gp = vr;
            *(f16x4*)(gp + PLANE_ELEMS) = vi;
        }
}

// ---------------- inverse: 2D IFFT (f16 complex -> real f32) ----------------
__global__ __launch_bounds__(64, 1) void inv_fft_kernel(const f16* __restrict__ oft,
                                                        float* __restrict__ out) {
    __shared__ float lre[64 * 65];
    __shared__ float lim[64 * 65];
    __shared__ float twc[64];
    __shared__ float tws[64];
    const int t = threadIdx.x;
    const int pl = blockIdx.x;
    const int set = pl >> 10;
    const int b = (pl >> 6) & 15;
    const int o = pl & 63;

    const float ang = (TWO_PI / 64.0f) * (float)t;
    twc[t] = cosf(ang);
    tws[t] = sinf(ang);    // inverse

    const f16* __restrict__ sre = oft + (size_t)pl * 4096;
    const f16* __restrict__ sim = sre + PLANE_ELEMS;
#pragma unroll
    for (int k = 0; k < 64; ++k) {
        lre[k * 65 + t] = (float)sre[k * 64 + t];
        lim[k * 65 + t] = (float)sim[k * 64 + t];
    }
    __syncthreads();

    float are[64], aim[64];
#pragma unroll
    for (int q = 0; q < 64; ++q) {
        const int r = bitrev6(q);
        are[q] = lre[t * 65 + r];
        aim[q] = lim[t * 65 + r];
    }
    fft64_reg(are, aim, twc, tws);
#pragma unroll
    for (int q = 0; q < 64; ++q) { lre[t * 65 + q] = are[q]; lim[t * 65 + q] = aim[q]; }
    __syncthreads();

#pragma unroll
    for (int q = 0; q < 64; ++q) {
        const int r = bitrev6(q);
        are[q] = lre[r * 65 + t];
        aim[q] = lim[r * 65 + t];
    }
    fft64_reg(are, aim, twc, tws);

    const int s1 = set ? (448 + o) : o;
    float* __restrict__ dst = out + ((size_t)(b * 512 + s1)) * 4096;
#pragma unroll
    for (int p = 0; p < 64; ++p)
        dst[p * 64 + t] = are[p] * (1.0f / 4096.0f);
}

// ---------------- zero-fill out[:, 64:448, :, :] ----------------
__global__ void zero_mid_kernel(float4* __restrict__ out) {
    const size_t per_b = (size_t)384 * 1024;  // float4 per batch mid-region
    const size_t i = (size_t)blockIdx.x * blockDim.x + threadIdx.x;
    if (i >= 16 * per_b) return;
    const size_t b = i / per_b;
    const size_t r = i - b * per_b;
    out[b * (512 * 1024) + 64 * 1024 + r] = make_float4(0.f, 0.f, 0.f, 0.f);
}

extern "C" void kernel_launch(void* const* d_in, const int* in_sizes, int n_in,
                              void* d_out, int out_size, void* d_ws, size_t ws_size,
                              hipStream_t stream) {
    const float* x  = (const float*)d_in[0];
    const float* w1 = (const float*)d_in[1];
    const float* w2 = (const float*)d_in[2];
    float* out = (float*)d_out;

    f16* xre16 = (f16*)d_ws;                    // 16.8 MB
    f16* xim16 = xre16 + PLANE_ELEMS;           // 16.8 MB
    f16* oft16 = xim16 + PLANE_ELEMS;           // 33.5 MB (re, then im at +PLANE)
    // requires ws_size >= ~67 MB

    fwd_fft_kernel<<<2048, 64, 0, stream>>>(x, xre16, xim16);
    mix_kernel<<<1024, 256, 0, stream>>>(xre16, w1, w2, oft16);
    inv_fft_kernel<<<2048, 64, 0, stream>>>(oft16, out);

    const int zthreads = 256;
    const int zblocks = (int)(((size_t)16 * 384 * 1024 + zthreads - 1) / zthreads);
    zero_mid_kernel<<<zblocks, zthreads, 0, stream>>>((float4*)out);
}